// Round 14
// baseline (224.886 us; speedup 1.0000x reference)
//
#include <hip/hip_runtime.h>
#include <hip/hip_cooperative_groups.h>
#include <stdint.h>

namespace cg = cooperative_groups;

#define GRID 192           // cooperative grid: 192 blocks x 1024 threads
#define K_SEL 512
#define NBOX 1536          // 3 * K_SEL
#define HBITS 13
#define HBINS 8192         // 13-bit monotone-key histogram (32 KB LDS)
#define NSHARD 128         // candidate-counter shards per scale
#define SEG 128            // entries per shard segment
#define HBLK 24            // hist blocks (2/6/16 per scale)
#define ICAP 56            // max tracked boxes per image (avg ~24)

// scale params
#define M0 32448           // 64*13*13*3
#define M1 129792          // 64*26*26*3
#define M2 519168          // 64*52*52*3
#define M_TOT (M0+M1+M2)   // 681408

// ws byte offsets — slices/THR/BOX/SKEY/TOPK rewritten every launch; CNT
// explicitly zeroed every launch -> poison-proof and replay-deterministic.
#define OFF_HSL  0u           // 24*8192*4 = 786432
#define OFF_CNT  786432u      // 3*128*4 = 1536 -> 787968
#define OFF_THR  787968u      // 32 -> 788000
#define OFF_CAND 788000u      // 3*128*128*8 = 393216 -> 1181216
#define OFF_BOX  1181216u     // 1536*7*4 = 43008 -> 1224224
#define OFF_SKEY 1224224u     // 1536*8 = 12288 -> 1236512
#define OFF_TOPK 1236512u     // 1536*8 = 12288 -> 1248800

typedef unsigned long long u64;
typedef uint32_t u32;
typedef uint16_t u16;

__device__ __forceinline__ float sigf(float x) { return 1.0f / (1.0f + expf(-x)); }

__device__ __forceinline__ u32 fmono(float f) {
    u32 u = __float_as_uint(f);
    return (u & 0x80000000u) ? ~u : (u | 0x80000000u);
}

// ---------------- LDS layouts (union: phases are serialized by syncs) ----------------
struct SortSh {
    u64 a_[4096];                  // 32 KB
    u32 scnt[NSHARD], spre[NSHARD];
};
struct TailSh {
    u64 sk[NBOX];                  // 12 KB (aliased by wvcnt after merge-rank)
    u16 srt[NBOX];
    float gx1[NBOX], gy1[NBOX], gx2[NBOX], gy2[NBOX], gar[NBOX];
    u32 meta[NBOX];                // img | cls<<8 | val<<16
    uint8_t gkeep[NBOX];
    u16 lists[64 * ICAP];
    u32 icnt[64];
};
union AllSh {
    u32 lh[HBINS];                 // hist
    u32 sum[1024];                 // scan
    SortSh sort;
    TailSh tail;
};                                  // max ~61.2 KB

// ---------------- phase: per-block LDS histogram -> private global slice ----------------
__device__ void dev_hist(int hb, const float* p0, const float* p1, const float* p2,
                         uint8_t* ws, u32* lh, int t) {
    for (int i = t; i < HBINS; i += 1024) lh[i] = 0;
    __syncthreads();
    int s, b0, nb;
    if (hb < 2)      { s = 0; b0 = hb;     nb = 2;  }
    else if (hb < 8) { s = 1; b0 = hb - 2; nb = 6;  }
    else             { s = 2; b0 = hb - 8; nb = 16; }
    int M = (s == 0) ? M0 : (s == 1) ? M1 : M2;
    int H = (s == 0) ? 13 : (s == 1) ? 26 : 52;
    int HW = H * H;
    const float* p = (s == 0) ? p0 : (s == 1) ? p1 : p2;
    for (int o = b0 * 1024 + t; o < M; o += nb * 1024) {
        int n = o / (3 * HW); int rem = o - n * 3 * HW;
        int a = rem / HW;     int pix = rem - a * HW;
        float conf = sigf(p[(size_t)(n * 255 + a * 85) * HW + pix]);
        atomicAdd(&lh[fmono(conf) >> (32 - HBITS)], 1u);
    }
    __syncthreads();
    u32* slice = (u32*)(ws + OFF_HSL) + (u32)hb * HBINS;
    for (int i = t; i < HBINS; i += 1024) slice[i] = lh[i];
}

// ---------------- phase: sum slices + suffix scan -> threshold bin ----------------
__device__ void dev_scan(int s, uint8_t* ws, u32* sum, int t) {
    int b0 = (s == 0) ? 0 : (s == 1) ? 2 : 8;
    int b1 = (s == 0) ? 2 : (s == 1) ? 8 : 24;
    u32 bins[8];
#pragma unroll
    for (int k = 0; k < 8; ++k) bins[k] = 0;
    for (int b = b0; b < b1; ++b) {
        const uint4* sl = (const uint4*)((u32*)(ws + OFF_HSL) + (u32)b * HBINS + t * 8);
        uint4 x = sl[0], y = sl[1];
        bins[0] += x.x; bins[1] += x.y; bins[2] += x.z; bins[3] += x.w;
        bins[4] += y.x; bins[5] += y.y; bins[6] += y.z; bins[7] += y.w;
    }
    u32 acc = 0;
#pragma unroll
    for (int k = 0; k < 8; ++k) acc += bins[k];
    sum[t] = acc;
    __syncthreads();
    for (int off = 1; off < 1024; off <<= 1) {        // inclusive suffix scan
        u32 v = (t + off < 1024) ? sum[t + off] : 0;
        __syncthreads();
        sum[t] += v;
        __syncthreads();
    }
    u32 excl = (t < 1023) ? sum[t + 1] : 0;
    u32 mine = sum[t] - excl;
    if (excl < K_SEL && excl + mine >= K_SEL) {
        u32 cum = excl; int thr = t * 8;
#pragma unroll
        for (int k = 7; k >= 0; --k) {
            cum += bins[k];
            if (cum >= K_SEL) { thr = t * 8 + k; break; }
        }
        ((u32*)(ws + OFF_THR))[s] = (u32)thr;
    }
}

// ---------------- phase: compact candidates (grid-stride, sharded counters) ----------------
__device__ void dev_compact(int bid, int t, const float* p0, const float* p1, const float* p2,
                            uint8_t* ws) {
    const u32* thr = (const u32*)(ws + OFF_THR);
    for (int i = bid * 1024 + t; i < M_TOT; i += GRID * 1024) {
        int s, o, H;
        if (i < M0)            { s = 0; o = i;           H = 13; }
        else if (i < M0 + M1)  { s = 1; o = i - M0;      H = 26; }
        else                   { s = 2; o = i - M0 - M1; H = 52; }
        const float* p = (s == 0) ? p0 : (s == 1) ? p1 : p2;
        int HW = H * H;
        int n = o / (3 * HW); int rem = o - n * 3 * HW;
        int a = rem / HW;     int pix = rem - a * HW;
        float conf = sigf(p[(size_t)(n * 255 + a * 85) * HW + pix]);
        u32 cb = fmono(conf);
        if ((cb >> (32 - HBITS)) >= thr[s]) {
            int c = n * (3 * HW) + pix * 3 + a;       // reference flat (n,h,w,a) index
            int idx = s * NSHARD + (bid & (NSHARD - 1));
            u32 pos = atomicAdd(&((u32*)(ws + OFF_CNT))[idx], 1u);
            if (pos < SEG) {
                u64 key = ((u64)cb << 32) | (u32)(~(u32)c);   // ties: smaller c first
                ((u64*)(ws + OFF_CAND))[(u32)idx * SEG + pos] = key;
            }
        }
    }
}

// ---------------- phase: shard-gather + LDS bitonic top-512 (desc) ----------------
__device__ void dev_sort(int s, uint8_t* ws, SortSh& S, int t) {
    if (t < NSHARD) {
        u32 v = ((u32*)(ws + OFF_CNT))[s * NSHARD + t];
        S.scnt[t] = (v > SEG) ? SEG : v;
        S.spre[t] = S.scnt[t];
    }
    __syncthreads();
    for (int off = 1; off < NSHARD; off <<= 1) {       // inclusive Hillis-Steele
        u32 v = (t >= off && t < NSHARD) ? S.spre[t - off] : 0;
        __syncthreads();
        if (t < NSHARD) S.spre[t] += v;
        __syncthreads();
    }
    u32 total = S.spre[NSHARD - 1];
    if (total > 4096) total = 4096;
    int n2 = K_SEL;
    while (n2 < (int)total) n2 <<= 1;
    for (int i = t; i < n2; i += 1024) S.a_[i] = 0ull;
    __syncthreads();
    if (t < NSHARD) {                                   // thread t copies shard t
        u32 base = S.spre[t] - S.scnt[t];
        const u64* seg = (const u64*)(ws + OFF_CAND) + (u32)(s * NSHARD + t) * SEG;
        for (u32 i = 0; i < S.scnt[t]; ++i)
            if (base + i < 4096) S.a_[base + i] = seg[i];
    }
    __syncthreads();
    for (int k = 2; k <= n2; k <<= 1) {                 // bitonic, descending
        for (int j = k >> 1; j > 0; j >>= 1) {
            for (int i = t; i < n2; i += 1024) {
                int ixj = i ^ j;
                if (ixj > i) {
                    bool desc = ((i & k) == 0);
                    u64 x = S.a_[i], y = S.a_[ixj];
                    if (desc ? (x < y) : (x > y)) { S.a_[i] = y; S.a_[ixj] = x; }
                }
            }
            __syncthreads();
        }
    }
    u64* topk = (u64*)(ws + OFF_TOPK) + s * K_SEL;
    for (int r = t; r < K_SEL; r += 1024) topk[r] = S.a_[r];
}

// ---------------- phase: decode one box with 16 lanes ----------------
__device__ void dev_decode(int g, int l,
                           const float* p0, const float* p1, const float* p2,
                           const float* a0, const float* a1, const float* a2, uint8_t* ws) {
    int s = g >> 9;
    int H = (s == 0) ? 13 : (s == 1) ? 26 : 52;
    float stride = (s == 0) ? 32.f : (s == 1) ? 16.f : 8.f;
    const float* p    = (s == 0) ? p0 : (s == 1) ? p1 : p2;
    const float* anch = (s == 0) ? a0 : (s == 1) ? a1 : a2;
    int HW = H * H, hw3 = HW * 3;
    u64 key = ((u64*)(ws + OFF_TOPK))[g];
    int c = (int)(~(u32)key);
    int n = c / hw3; int rem = c - n * hw3;
    int pix = rem / 3; int aa = rem - pix * 3;
    size_t base = (size_t)(n * 255 + aa * 85) * HW + pix;
    // lane l: classes l, l+16, ..., l+64 (ascending -> strict > keeps lowest in-lane)
    float best = -INFINITY; int bi = 0x7FFFFFFF;
#pragma unroll
    for (int m = 0; m < 5; ++m) {
        int k2 = l + m * 16;
        float vv = p[base + (size_t)(5 + k2) * HW];
        if (vv > best) { best = vv; bi = k2; }
    }
    float vload = (l < 5) ? p[base + (size_t)l * HW] : 0.f;
    // argmax reduce over 16 lanes: val >, tie -> lower class idx (first occurrence)
#pragma unroll
    for (int off = 8; off > 0; off >>= 1) {
        float ov = __shfl_down(best, off, 16);
        int oi = __shfl_down(bi, off, 16);
        if (ov > best || (ov == best && oi < bi)) { best = ov; bi = oi; }
    }
    float v0 = __shfl(vload, 0, 16);
    float v1 = __shfl(vload, 1, 16);
    float v2 = __shfl(vload, 2, 16);
    float v3 = __shfl(vload, 3, 16);
    float v4 = __shfl(vload, 4, 16);
    if (l == 0) {
        int h = pix / H, w = pix - h * H;
        float conf = sigf(v0);
        float cx = ((float)w + sigf(v1)) * stride;
        float cy = ((float)h + sigf(v2)) * stride;
        float bw = anch[aa * 2 + 0] * expf(v3);
        float bh = anch[aa * 2 + 1] * expf(v4);
        float* box = (float*)(ws + OFF_BOX) + g * 7;
        box[0] = (float)n; box[1] = conf; box[2] = cx; box[3] = cy;
        box[4] = bw; box[5] = bh; box[6] = (float)bi;
        u32 mono = (conf > 0.5f) ? fmono(conf) : fmono(-INFINITY);
        ((u64*)(ws + OFF_SKEY))[g] = ((u64)mono << 32) | (u32)(~(u32)g);  // ties: smaller pos
    }
}

// ---------------- phase: merge-rank + ballot image-rank + wave-parallel NMS + output ----------------
__device__ void dev_tail(uint8_t* ws, float* out, TailSh& T, int t) {
    u32* wvcnt = (u32*)T.sk;                           // alias after merge-rank
    u64* skey = (u64*)(ws + OFF_SKEY);
    for (int i = t; i < NBOX; i += 1024) T.sk[i] = skey[i];
    __syncthreads();
    // merge-rank: grank = r + count of strictly-greater keys in the other two lists
    for (int i = t; i < NBOX; i += 1024) {
        int s = i >> 9, r = i & 511;
        u64 K = T.sk[i];
        int g = r;
#pragma unroll
        for (int s2 = 0; s2 < 3; ++s2) {
            if (s2 == s) continue;
            const u64* seg = &T.sk[s2 << 9];
            int lo = 0, hi = 512;
            while (lo < hi) {                          // first idx with seg[idx] <= K
                int mid = (lo + hi) >> 1;
                if (seg[mid] > K) lo = mid + 1; else hi = mid;
            }
            g += lo;
        }
        T.srt[g] = (u16)i;
    }
    __syncthreads();                                   // sk dead; wvcnt aliases it
    const float* box = (const float*)(ws + OFF_BOX);
    for (int i = t; i < NBOX; i += 1024) {
        int pos = T.srt[i];
        float b0 = box[pos * 7 + 0], b1 = box[pos * 7 + 1], b2 = box[pos * 7 + 2];
        float b3 = box[pos * 7 + 3], b4 = box[pos * 7 + 4], b5 = box[pos * 7 + 5];
        float b6 = box[pos * 7 + 6];
        T.gx1[i] = b2 - b4 * 0.5f;  T.gy1[i] = b3 - b5 * 0.5f;
        T.gx2[i] = b2 + b4 * 0.5f;  T.gy2[i] = b3 + b5 * 0.5f;
        T.gar[i] = b4 * b5;
        T.meta[i] = (u32)(int)b0 | ((u32)(int)b6 << 8) | ((b1 > 0.5f) ? (1u << 16) : 0u);
        T.gkeep[i] = 0;
        wvcnt[i] = 0;
    }
    __syncthreads();
    // phase 1: per-(sorted-wave, image) counts via 6-ballot match-any
#pragma unroll
    for (int pass = 0; pass < 2; ++pass) {
        int ii = t + pass * 1024;
        u32 img = (ii < NBOX) ? (T.meta[ii] & 63u) : 0u;
        u64 mask = ~0ull;
#pragma unroll
        for (int b = 0; b < 6; ++b) {
            bool bit = (img >> b) & 1u;
            u64 bal = __ballot(bit);
            mask &= bit ? bal : ~bal;
        }
        if (ii < NBOX) {
            int lane = ii & 63;
            int wrank = __popcll(mask & ((1ull << lane) - 1ull));
            if (wrank == 0) wvcnt[(ii >> 6) * 64 + img] = (u32)__popcll(mask);
        }
    }
    __syncthreads();
    // phase 2: global in-image rank -> lists; icnt by first 64 threads
    if (t < 64) {
        u32 c = 0;
        for (int w = 0; w < 24; ++w) c += wvcnt[w * 64 + t];
        T.icnt[t] = c;
    }
#pragma unroll
    for (int pass = 0; pass < 2; ++pass) {
        int ii = t + pass * 1024;
        u32 img = (ii < NBOX) ? (T.meta[ii] & 63u) : 0u;
        u64 mask = ~0ull;
#pragma unroll
        for (int b = 0; b < 6; ++b) {
            bool bit = (img >> b) & 1u;
            u64 bal = __ballot(bit);
            mask &= bit ? bal : ~bal;
        }
        if (ii < NBOX) {
            int lane = ii & 63;
            int wvv = ii >> 6;
            int r = __popcll(mask & ((1ull << lane) - 1ull));
            for (int w = 0; w < wvv; ++w) r += (int)wvcnt[w * 64 + img];
            if (r < ICAP) T.lists[img * ICAP + r] = (u16)ii;
        }
    }
    __syncthreads();
    // phase 3: NMS — wave wv handles images 4*wv..4*wv+3; lane = box rank
    {
        int wv = t >> 6, lane = t & 63;
        for (int im = wv * 4; im < wv * 4 + 4; ++im) {
            int cnt = (int)T.icnt[im]; if (cnt > ICAP) cnt = ICAP;
            float x1 = 0, y1 = 0, x2 = 0, y2 = 0, ar = 0;
            u32 cl = 0; int u = -1; bool val = false;
            if (lane < cnt) {
                u = T.lists[im * ICAP + lane];
                x1 = T.gx1[u]; y1 = T.gy1[u]; x2 = T.gx2[u]; y2 = T.gy2[u]; ar = T.gar[u];
                u32 m = T.meta[u]; cl = (m >> 8) & 0xFFu; val = (m >> 16) & 1u;
            }
            u64 valmask = __ballot(val);
            u64 keptmask = 0;
            for (int a = 0; a < cnt; ++a) {
                float ax1 = __shfl(x1, a), ay1 = __shfl(y1, a);
                float ax2 = __shfl(x2, a), ay2 = __shfl(y2, a);
                float aar = __shfl(ar, a);
                u32 acl = (u32)__shfl((int)cl, a);
                float ix1 = fmaxf(x1, ax1), iy1 = fmaxf(y1, ay1);
                float ix2 = fminf(x2, ax2), iy2 = fminf(y2, ay2);
                float iw = fmaxf(ix2 - ix1, 0.f), ih = fmaxf(iy2 - iy1, 0.f);
                float inter = iw * ih;
                float iou = inter / (ar + aar - inter + 1e-9f);
                bool viol = (lane < a) && ((keptmask >> lane) & 1ull) &&
                            (cl == acl) && (iou > 0.1f);
                u64 bal = __ballot(viol);
                bool kept = ((valmask >> a) & 1ull) && (bal == 0ull);
                if (kept) keptmask |= (1ull << a);
            }
            if (lane < cnt) T.gkeep[u] = (uint8_t)((keptmask >> lane) & 1ull);
        }
    }
    __syncthreads();
    for (int i = t; i < NBOX; i += 1024) {
        float kf = T.gkeep[i] ? 1.f : 0.f;
        int pos = T.srt[i];
        for (int k = 0; k < 7; ++k) out[i * 7 + k] = box[pos * 7 + k] * kf;
        out[NBOX * 7 + i] = kf;
    }
}

// ---------------- the single cooperative kernel ----------------
__global__ __launch_bounds__(1024) void k_all(const float* p0, const float* p1, const float* p2,
                                              const float* a0, const float* a1, const float* a2,
                                              uint8_t* ws, float* out) {
    __shared__ AllSh sh;
    cg::grid_group grid = cg::this_grid();
    int bid = blockIdx.x, t = threadIdx.x;

    // A: hist (blocks 0..23, LDS hist -> private slice) + zero CNT (block 24)
    if (bid < HBLK) dev_hist(bid, p0, p1, p2, ws, sh.lh, t);
    if (bid == HBLK && t < 3 * NSHARD) ((u32*)(ws + OFF_CNT))[t] = 0;
    grid.sync();

    // B: scan (blocks 0..2) -> THR
    if (bid < 3) dev_scan(bid, ws, sh.sum, t);
    grid.sync();

    // C: compact (all blocks, grid-stride)
    dev_compact(bid, t, p0, p1, p2, ws);
    grid.sync();

    // D: sort (blocks 0..2) -> TOPK
    if (bid < 3) dev_sort(bid, ws, sh.sort, t);
    grid.sync();

    // E: decode (all blocks: 8 boxes x 16 lanes) -> BOX, SKEY
    if (t < 128) dev_decode(bid * 8 + (t >> 4), t & 15, p0, p1, p2, a0, a1, a2, ws);
    grid.sync();

    // F: tail (block 0) -> out
    if (bid == 0) dev_tail(ws, out, sh.tail, t);
}

// ---------------- fallback kernels (same device code, classic launches) ----------------
__global__ __launch_bounds__(1024) void fb_hist(const float* p0, const float* p1, const float* p2,
                                                uint8_t* ws) {
    __shared__ u32 lh[HBINS];
    if (blockIdx.x < HBLK) dev_hist(blockIdx.x, p0, p1, p2, ws, lh, threadIdx.x);
    else if (threadIdx.x < 3 * NSHARD) ((u32*)(ws + OFF_CNT))[threadIdx.x] = 0;
}
__global__ __launch_bounds__(1024) void fb_scan(uint8_t* ws) {
    __shared__ u32 sum[1024];
    dev_scan(blockIdx.x, ws, sum, threadIdx.x);
}
__global__ __launch_bounds__(1024) void fb_compact(const float* p0, const float* p1, const float* p2,
                                                   uint8_t* ws) {
    dev_compact(blockIdx.x, threadIdx.x, p0, p1, p2, ws);
}
__global__ __launch_bounds__(1024) void fb_sort(uint8_t* ws) {
    __shared__ SortSh S;
    dev_sort(blockIdx.x, ws, S, threadIdx.x);
}
__global__ __launch_bounds__(128) void fb_decode(const float* p0, const float* p1, const float* p2,
                                                 const float* a0, const float* a1, const float* a2,
                                                 uint8_t* ws) {
    dev_decode(blockIdx.x * 8 + (threadIdx.x >> 4), threadIdx.x & 15,
               p0, p1, p2, a0, a1, a2, ws);
}
__global__ __launch_bounds__(1024) void fb_tail(uint8_t* ws, float* out) {
    __shared__ TailSh T;
    dev_tail(ws, out, T, threadIdx.x);
}

extern "C" void kernel_launch(void* const* d_in, const int* in_sizes, int n_in,
                              void* d_out, int out_size, void* d_ws, size_t ws_size,
                              hipStream_t stream) {
    const float* p0 = (const float*)d_in[0];
    const float* p1 = (const float*)d_in[1];
    const float* p2 = (const float*)d_in[2];
    const float* a0 = (const float*)d_in[3];
    const float* a1 = (const float*)d_in[4];
    const float* a2 = (const float*)d_in[5];
    uint8_t* ws = (uint8_t*)d_ws;
    float* out = (float*)d_out;
    (void)in_sizes; (void)n_in; (void)out_size; (void)ws_size;

    void* args[] = { (void*)&p0, (void*)&p1, (void*)&p2,
                     (void*)&a0, (void*)&a1, (void*)&a2,
                     (void*)&ws, (void*)&out };
    hipError_t e = hipLaunchCooperativeKernel((const void*)k_all, dim3(GRID), dim3(1024),
                                              args, 0, stream);
    if (e != hipSuccess) {
        (void)hipGetLastError();   // clear sticky error; deterministic fallback path
        fb_hist   <<<HBLK + 1, 1024, 0, stream>>>(p0, p1, p2, ws);
        fb_scan   <<<3, 1024, 0, stream>>>(ws);
        fb_compact<<<GRID, 1024, 0, stream>>>(p0, p1, p2, ws);
        fb_sort   <<<3, 1024, 0, stream>>>(ws);
        fb_decode <<<192, 128, 0, stream>>>(p0, p1, p2, a0, a1, a2, ws);
        fb_tail   <<<1, 1024, 0, stream>>>(ws, out);
    }
}

// Round 15
// 125.423 us; speedup vs baseline: 1.7930x; 1.7930x over previous
//
#include <hip/hip_runtime.h>
#include <stdint.h>

#define K_SEL 512
#define NBOX 1536          // 3 * K_SEL
#define HBITS 13
#define HBINS 8192         // 13-bit monotone-key histogram (32 KB LDS)
#define NSHARD 128         // candidate-counter shards per scale
#define SEG 128            // entries per shard segment
#define HBLK 24            // hist blocks (2/6/16 per scale)
#define ICAP 56            // max tracked boxes per image (avg ~24)

// scale params
#define M0 32448           // 64*13*13*3
#define M1 129792          // 64*26*26*3
#define M2 519168          // 64*52*52*3
#define M_TOT (M0+M1+M2)   // 681408

// ws byte offsets — slices/BOX/SKEY unconditionally rewritten every launch;
// CNT zeroed by k_hist block 0 (separate dispatch before use) -> poison-proof.
#define OFF_HSL  0u           // 24*8192*4 = 786432
#define OFF_CNT  786432u      // 3*128*4 = 1536 -> 787968
#define OFF_CAND 787968u      // 3*128*128*8 = 393216 -> 1181184
#define OFF_BOX  1181184u     // 1536*7*4 = 43008 -> 1224192
#define OFF_SKEY 1224192u     // 1536*8 = 12288 -> 1236480

typedef unsigned long long u64;
typedef uint32_t u32;
typedef uint16_t u16;

__device__ __forceinline__ float sigf(float x) { return 1.0f / (1.0f + expf(-x)); }

__device__ __forceinline__ u32 fmono(float f) {
    u32 u = __float_as_uint(f);
    return (u & 0x80000000u) ? ~u : (u | 0x80000000u);
}

// ---------------- kernel 1: per-block LDS histogram -> private global slice ----------------
// Plane-order (n,a,pix): coalesced conf reads. Block 0 also zeroes shard counters
// (used first by kernel 2, a later dispatch).
__global__ __launch_bounds__(1024) void k_hist(const float* p0, const float* p1, const float* p2,
                                               uint8_t* ws) {
    __shared__ u32 lh[HBINS];
    int t = threadIdx.x;
    for (int i = t; i < HBINS; i += 1024) lh[i] = 0;
    if (blockIdx.x == 0 && t < 3 * NSHARD) ((u32*)(ws + OFF_CNT))[t] = 0;
    __syncthreads();
    int b = blockIdx.x, s, b0, nb;
    if (b < 2)      { s = 0; b0 = b;     nb = 2;  }
    else if (b < 8) { s = 1; b0 = b - 2; nb = 6;  }
    else            { s = 2; b0 = b - 8; nb = 16; }
    int M = (s == 0) ? M0 : (s == 1) ? M1 : M2;
    int H = (s == 0) ? 13 : (s == 1) ? 26 : 52;
    int HW = H * H;
    const float* p = (s == 0) ? p0 : (s == 1) ? p1 : p2;
    for (int o = b0 * 1024 + t; o < M; o += nb * 1024) {
        int n = o / (3 * HW); int rem = o - n * 3 * HW;
        int a = rem / HW;     int pix = rem - a * HW;
        float conf = sigf(p[(size_t)(n * 255 + a * 85) * HW + pix]);
        atomicAdd(&lh[fmono(conf) >> (32 - HBITS)], 1u);
    }
    __syncthreads();
    u32* slice = (u32*)(ws + OFF_HSL) + (u32)b * HBINS;
    for (int i = t; i < HBINS; i += 1024) slice[i] = lh[i];
}

// ---------------- kernel 2: inline threshold-scan + compact (scale-aligned blocks) ----------------
// Each block redundantly sums its scale's hist slices (L2/L3-resident) and
// suffix-scans them in LDS -> THR in a register (no global THR, no extra
// dispatch). Then compacts its slice of the scale with sharded counters.
__global__ __launch_bounds__(1024) void k_compact(const float* p0, const float* p1, const float* p2,
                                                  uint8_t* ws) {
    __shared__ u32 sum[1024];
    __shared__ u32 thr_sh;
    int bid = blockIdx.x, t = threadIdx.x;
    int s, lb, nb;
    if (bid < 12)      { s = 0; lb = bid;      nb = 12;  }
    else if (bid < 60) { s = 1; lb = bid - 12; nb = 48;  }
    else               { s = 2; lb = bid - 60; nb = 196; }
    int sb0 = (s == 0) ? 0 : (s == 1) ? 2 : 8;
    int sb1 = (s == 0) ? 2 : (s == 1) ? 8 : 24;
    // sum this scale's slices: thread t owns bins [t*8, t*8+8)
    u32 bins[8];
#pragma unroll
    for (int k = 0; k < 8; ++k) bins[k] = 0;
    for (int b = sb0; b < sb1; ++b) {
        const uint4* sl = (const uint4*)((u32*)(ws + OFF_HSL) + (u32)b * HBINS + t * 8);
        uint4 x = sl[0], y = sl[1];
        bins[0] += x.x; bins[1] += x.y; bins[2] += x.z; bins[3] += x.w;
        bins[4] += y.x; bins[5] += y.y; bins[6] += y.z; bins[7] += y.w;
    }
    u32 acc = 0;
#pragma unroll
    for (int k = 0; k < 8; ++k) acc += bins[k];
    sum[t] = acc;
    __syncthreads();
    for (int off = 1; off < 1024; off <<= 1) {        // inclusive suffix scan
        u32 v = (t + off < 1024) ? sum[t + off] : 0;
        __syncthreads();
        sum[t] += v;
        __syncthreads();
    }
    u32 excl = (t < 1023) ? sum[t + 1] : 0;
    u32 mine = sum[t] - excl;
    if (excl < K_SEL && excl + mine >= K_SEL) {       // exactly one winner thread
        u32 cum = excl; int thr = t * 8;
#pragma unroll
        for (int k = 7; k >= 0; --k) {
            cum += bins[k];
            if (cum >= K_SEL) { thr = t * 8 + k; break; }
        }
        thr_sh = (u32)thr;
    }
    __syncthreads();
    u32 thr = thr_sh;
    // compact this block's slice of the scale
    int M = (s == 0) ? M0 : (s == 1) ? M1 : M2;
    int H = (s == 0) ? 13 : (s == 1) ? 26 : 52;
    int HW = H * H;
    const float* p = (s == 0) ? p0 : (s == 1) ? p1 : p2;
    for (int o = lb * 1024 + t; o < M; o += nb * 1024) {
        int n = o / (3 * HW); int rem = o - n * 3 * HW;
        int a = rem / HW;     int pix = rem - a * HW;
        float conf = sigf(p[(size_t)(n * 255 + a * 85) * HW + pix]);
        u32 cb = fmono(conf);
        if ((cb >> (32 - HBITS)) >= thr) {
            int c = n * (3 * HW) + pix * 3 + a;       // reference flat (n,h,w,a) index
            int idx = s * NSHARD + (bid & (NSHARD - 1));
            u32 pos = atomicAdd(&((u32*)(ws + OFF_CNT))[idx], 1u);
            if (pos < SEG) {
                u64 key = ((u64)cb << 32) | (u32)(~(u32)c);   // ties: smaller c first
                ((u64*)(ws + OFF_CAND))[(u32)idx * SEG + pos] = key;
            }
        }
    }
}

// ---------------- kernel 3: redundant shard-gather + LDS bitonic + decode 8 boxes ----------------
// 192 blocks = 3 scales x 64. Each block sorts its scale's candidates (<=4096,
// LDS-loop bitonic — validated, no register-array spill) and decodes its 8-box
// slice with 16 lanes per box. Redundant sorting is free in wall time (parallel
// CUs); removes a dispatch and the TOPK global round-trip.
__global__ __launch_bounds__(1024) void k_sortdec(const float* p0, const float* p1, const float* p2,
                                                  const float* a0, const float* a1, const float* a2,
                                                  uint8_t* ws) {
    int s = blockIdx.x >> 6, sub = blockIdx.x & 63;
    __shared__ u64 a_[4096];               // 32 KB
    __shared__ u32 scnt[NSHARD], spre[NSHARD];
    int t = threadIdx.x;
    if (t < NSHARD) {
        u32 v = ((u32*)(ws + OFF_CNT))[s * NSHARD + t];
        scnt[t] = (v > SEG) ? SEG : v;
        spre[t] = scnt[t];
    }
    __syncthreads();
    for (int off = 1; off < NSHARD; off <<= 1) {       // inclusive Hillis-Steele
        u32 v = (t >= off && t < NSHARD) ? spre[t - off] : 0;
        __syncthreads();
        if (t < NSHARD) spre[t] += v;
        __syncthreads();
    }
    u32 total = spre[NSHARD - 1];
    if (total > 4096) total = 4096;
    int n2 = K_SEL;
    while (n2 < (int)total) n2 <<= 1;
    for (int i = t; i < n2; i += 1024) a_[i] = 0ull;
    __syncthreads();
    if (t < NSHARD) {                                   // thread t copies shard t
        u32 base = spre[t] - scnt[t];
        const u64* seg = (const u64*)(ws + OFF_CAND) + (u32)(s * NSHARD + t) * SEG;
        for (u32 i = 0; i < scnt[t]; ++i)
            if (base + i < 4096) a_[base + i] = seg[i];
    }
    __syncthreads();
    for (int k = 2; k <= n2; k <<= 1) {                 // bitonic, descending
        for (int j = k >> 1; j > 0; j >>= 1) {
            for (int i = t; i < n2; i += 1024) {
                int ixj = i ^ j;
                if (ixj > i) {
                    bool desc = ((i & k) == 0);
                    u64 x = a_[i], y = a_[ixj];
                    if (desc ? (x < y) : (x > y)) { a_[i] = y; a_[ixj] = x; }
                }
            }
            __syncthreads();
        }
    }
    // decode this block's 8-box slice; 16 lanes per box (t < 128 active)
    if (t >= 128) return;
    int g16 = t >> 4, l = t & 15;
    int rloc = sub * 8 + g16;                          // rank within scale
    int H = (s == 0) ? 13 : (s == 1) ? 26 : 52;
    float stride = (s == 0) ? 32.f : (s == 1) ? 16.f : 8.f;
    const float* p    = (s == 0) ? p0 : (s == 1) ? p1 : p2;
    const float* anch = (s == 0) ? a0 : (s == 1) ? a1 : a2;
    int HW = H * H, hw3 = HW * 3;
    u64 key = a_[rloc];
    int c = (int)(~(u32)key);
    int n = c / hw3; int rem = c - n * hw3;
    int pix = rem / 3; int aa = rem - pix * 3;
    size_t base = (size_t)(n * 255 + aa * 85) * HW + pix;
    // lane l: classes l, l+16, ..., l+64 (ascending -> strict > keeps lowest in-lane)
    float best = -INFINITY; int bi = 0x7FFFFFFF;
#pragma unroll
    for (int m = 0; m < 5; ++m) {
        int k2 = l + m * 16;
        float vv = p[base + (size_t)(5 + k2) * HW];
        if (vv > best) { best = vv; bi = k2; }
    }
    float vload = (l < 5) ? p[base + (size_t)l * HW] : 0.f;
    // argmax reduce over 16 lanes: val >, tie -> lower class idx (first occurrence)
#pragma unroll
    for (int off = 8; off > 0; off >>= 1) {
        float ov = __shfl_down(best, off, 16);
        int oi = __shfl_down(bi, off, 16);
        if (ov > best || (ov == best && oi < bi)) { best = ov; bi = oi; }
    }
    float v0 = __shfl(vload, 0, 16);
    float v1 = __shfl(vload, 1, 16);
    float v2 = __shfl(vload, 2, 16);
    float v3 = __shfl(vload, 3, 16);
    float v4 = __shfl(vload, 4, 16);
    if (l == 0) {
        int h = pix / H, w = pix - h * H;
        float conf = sigf(v0);
        float cx = ((float)w + sigf(v1)) * stride;
        float cy = ((float)h + sigf(v2)) * stride;
        float bw = anch[aa * 2 + 0] * expf(v3);
        float bh = anch[aa * 2 + 1] * expf(v4);
        int gi = s * K_SEL + rloc;
        float* box = (float*)(ws + OFF_BOX) + gi * 7;
        box[0] = (float)n; box[1] = conf; box[2] = cx; box[3] = cy;
        box[4] = bw; box[5] = bh; box[6] = (float)bi;
        u32 mono = (conf > 0.5f) ? fmono(conf) : fmono(-INFINITY);
        ((u64*)(ws + OFF_SKEY))[gi] = ((u64)mono << 32) | (u32)(~(u32)gi);  // ties: smaller pos
    }
}

// ---------------- kernel 4: merge-rank + ballot image-rank + wave-parallel NMS + output ----------------
__global__ __launch_bounds__(1024) void k_tail(uint8_t* ws, float* out) {
    __shared__ u64 sk[NBOX];                                        // 12 KB (aliased by wvcnt later)
    __shared__ u16 srt[NBOX];
    __shared__ float gx1[NBOX], gy1[NBOX], gx2[NBOX], gy2[NBOX], gar[NBOX];
    __shared__ u32 meta[NBOX];                                      // img | cls<<8 | val<<16
    __shared__ uint8_t gkeep[NBOX];
    __shared__ u16 lists[64 * ICAP];
    __shared__ u32 icnt[64];
    u32* wvcnt = (u32*)sk;                                          // alias after merge-rank
    int t = threadIdx.x;
    u64* skey = (u64*)(ws + OFF_SKEY);
    for (int i = t; i < NBOX; i += 1024) sk[i] = skey[i];
    __syncthreads();
    // merge-rank: grank = r + count of strictly-greater keys in the other two lists
    for (int i = t; i < NBOX; i += 1024) {
        int s = i >> 9, r = i & 511;
        u64 K = sk[i];
        int g = r;
#pragma unroll
        for (int s2 = 0; s2 < 3; ++s2) {
            if (s2 == s) continue;
            const u64* seg = &sk[s2 << 9];
            int lo = 0, hi = 512;
            while (lo < hi) {                          // first idx with seg[idx] <= K
                int mid = (lo + hi) >> 1;
                if (seg[mid] > K) lo = mid + 1; else hi = mid;
            }
            g += lo;
        }
        srt[g] = (u16)i;
    }
    __syncthreads();                                   // sk dead; wvcnt aliases it
    const float* box = (const float*)(ws + OFF_BOX);
    for (int i = t; i < NBOX; i += 1024) {
        int pos = srt[i];
        float b0 = box[pos * 7 + 0], b1 = box[pos * 7 + 1], b2 = box[pos * 7 + 2];
        float b3 = box[pos * 7 + 3], b4 = box[pos * 7 + 4], b5 = box[pos * 7 + 5];
        float b6 = box[pos * 7 + 6];
        gx1[i] = b2 - b4 * 0.5f;  gy1[i] = b3 - b5 * 0.5f;
        gx2[i] = b2 + b4 * 0.5f;  gy2[i] = b3 + b5 * 0.5f;
        gar[i] = b4 * b5;
        meta[i] = (u32)(int)b0 | ((u32)(int)b6 << 8) | ((b1 > 0.5f) ? (1u << 16) : 0u);
        gkeep[i] = 0;
        wvcnt[i] = 0;
    }
    __syncthreads();
    // phase 1: per-(sorted-wave, image) counts via 6-ballot match-any
#pragma unroll
    for (int pass = 0; pass < 2; ++pass) {
        int ii = t + pass * 1024;
        u32 img = (ii < NBOX) ? (meta[ii] & 63u) : 0u;
        u64 mask = ~0ull;
#pragma unroll
        for (int b = 0; b < 6; ++b) {
            bool bit = (img >> b) & 1u;
            u64 bal = __ballot(bit);
            mask &= bit ? bal : ~bal;
        }
        if (ii < NBOX) {
            int lane = ii & 63;
            int wrank = __popcll(mask & ((1ull << lane) - 1ull));
            if (wrank == 0) wvcnt[(ii >> 6) * 64 + img] = (u32)__popcll(mask);
        }
    }
    __syncthreads();
    // phase 2: global in-image rank -> lists; icnt by first 64 threads
    if (t < 64) {
        u32 c = 0;
        for (int w = 0; w < 24; ++w) c += wvcnt[w * 64 + t];
        icnt[t] = c;
    }
#pragma unroll
    for (int pass = 0; pass < 2; ++pass) {
        int ii = t + pass * 1024;
        u32 img = (ii < NBOX) ? (meta[ii] & 63u) : 0u;
        u64 mask = ~0ull;
#pragma unroll
        for (int b = 0; b < 6; ++b) {
            bool bit = (img >> b) & 1u;
            u64 bal = __ballot(bit);
            mask &= bit ? bal : ~bal;
        }
        if (ii < NBOX) {
            int lane = ii & 63;
            int wvv = ii >> 6;
            int r = __popcll(mask & ((1ull << lane) - 1ull));
            for (int w = 0; w < wvv; ++w) r += (int)wvcnt[w * 64 + img];
            if (r < ICAP) lists[img * ICAP + r] = (u16)ii;
        }
    }
    __syncthreads();
    // phase 3: NMS — wave wv handles images 4*wv..4*wv+3; lane = box rank
    {
        int wv = t >> 6, lane = t & 63;
        for (int im = wv * 4; im < wv * 4 + 4; ++im) {
            int cnt = (int)icnt[im]; if (cnt > ICAP) cnt = ICAP;
            float x1 = 0, y1 = 0, x2 = 0, y2 = 0, ar = 0;
            u32 cl = 0; int u = -1; bool val = false;
            if (lane < cnt) {
                u = lists[im * ICAP + lane];
                x1 = gx1[u]; y1 = gy1[u]; x2 = gx2[u]; y2 = gy2[u]; ar = gar[u];
                u32 m = meta[u]; cl = (m >> 8) & 0xFFu; val = (m >> 16) & 1u;
            }
            u64 valmask = __ballot(val);
            u64 keptmask = 0;
            for (int a = 0; a < cnt; ++a) {
                float ax1 = __shfl(x1, a), ay1 = __shfl(y1, a);
                float ax2 = __shfl(x2, a), ay2 = __shfl(y2, a);
                float aar = __shfl(ar, a);
                u32 acl = (u32)__shfl((int)cl, a);
                float ix1 = fmaxf(x1, ax1), iy1 = fmaxf(y1, ay1);
                float ix2 = fminf(x2, ax2), iy2 = fminf(y2, ay2);
                float iw = fmaxf(ix2 - ix1, 0.f), ih = fmaxf(iy2 - iy1, 0.f);
                float inter = iw * ih;
                float iou = inter / (ar + aar - inter + 1e-9f);
                bool viol = (lane < a) && ((keptmask >> lane) & 1ull) &&
                            (cl == acl) && (iou > 0.1f);
                u64 bal = __ballot(viol);
                bool kept = ((valmask >> a) & 1ull) && (bal == 0ull);
                if (kept) keptmask |= (1ull << a);
            }
            if (lane < cnt) gkeep[u] = (uint8_t)((keptmask >> lane) & 1ull);
        }
    }
    __syncthreads();
    for (int i = t; i < NBOX; i += 1024) {
        float kf = gkeep[i] ? 1.f : 0.f;
        int pos = srt[i];
        for (int k = 0; k < 7; ++k) out[i * 7 + k] = box[pos * 7 + k] * kf;
        out[NBOX * 7 + i] = kf;
    }
}

extern "C" void kernel_launch(void* const* d_in, const int* in_sizes, int n_in,
                              void* d_out, int out_size, void* d_ws, size_t ws_size,
                              hipStream_t stream) {
    const float* p0 = (const float*)d_in[0];
    const float* p1 = (const float*)d_in[1];
    const float* p2 = (const float*)d_in[2];
    const float* a0 = (const float*)d_in[3];
    const float* a1 = (const float*)d_in[4];
    const float* a2 = (const float*)d_in[5];
    uint8_t* ws = (uint8_t*)d_ws;
    float* out = (float*)d_out;

    k_hist   <<<HBLK, 1024, 0, stream>>>(p0, p1, p2, ws);
    k_compact<<<256, 1024, 0, stream>>>(p0, p1, p2, ws);
    k_sortdec<<<192, 1024, 0, stream>>>(p0, p1, p2, a0, a1, a2, ws);
    k_tail   <<<1, 1024, 0, stream>>>(ws, out);
}